// Round 7
// baseline (347.420 us; speedup 1.0000x reference)
//
#include <hip/hip_runtime.h>
#include <hip/hip_fp16.h>

#define NF 128   // feature dim, fixed by the problem

typedef _Float16 half8 __attribute__((ext_vector_type(8)));
typedef float    floatx4 __attribute__((ext_vector_type(4)));
typedef float    floatx2 __attribute__((ext_vector_type(2)));

// ---------------- prep: zero cnt + convert/transpose W1,W2 to fp16 ----------------
__global__ __launch_bounds__(256) void prep_k(
    int* __restrict__ cnt, int n, int nb,
    const float* __restrict__ W1, const float* __restrict__ W2,
    __half* __restrict__ WT1, __half* __restrict__ WT2)
{
    int b = blockIdx.x;
    if (b < nb) {
        int i = b * 256 + threadIdx.x;
        if (i < n) cnt[i] = 0;
    } else {
        int idx = (b - nb) * 256 + threadIdx.x;   // 0..32767
        const float* W = (idx < 16384) ? W1 : W2;
        __half* WT     = (idx < 16384) ? WT1 : WT2;
        int j = idx & 16383;
        int nn = j & 127, k = j >> 7;
        WT[nn * NF + k] = __float2half(W[k * NF + nn]);   // WT[n][k] = W[k][n]
    }
}

__global__ void count_k(const int* __restrict__ dst, int* __restrict__ cnt, int E, int N) {
    int e = blockIdx.x * 256 + threadIdx.x;
    if (e < E) {
        int d = dst[e];
        if ((unsigned)d < (unsigned)N) atomicAdd(&cnt[d], 1);
    }
}

// Phase 1: per-256-chunk local exclusive scan (into rowptr) + block totals + dinv.
__global__ __launch_bounds__(256) void pscan_local(
    const int* __restrict__ cnt, float* __restrict__ dinv,
    int* __restrict__ rowptr, int* __restrict__ blocksum, int n)
{
    __shared__ int sm[256];
    int tid = threadIdx.x;
    int i = blockIdx.x * 256 + tid;
    int v = (i < n) ? cnt[i] : 0;
    if (i < n) dinv[i] = rsqrtf((float)v + 1.0f);  // +1 = self-loop
    sm[tid] = v;
    __syncthreads();
    #pragma unroll
    for (int d = 1; d < 256; d <<= 1) {
        int t = (tid >= d) ? sm[tid - d] : 0;
        __syncthreads();
        sm[tid] += t;
        __syncthreads();
    }
    if (i < n) rowptr[i] = sm[tid] - v;            // local exclusive prefix
    if (tid == 255) blocksum[blockIdx.x] = sm[255];
}

// Phase 2: single-block exclusive scan of the block sums (nb <= 256).
__global__ __launch_bounds__(256) void scan_blk(int* __restrict__ blocksum, int nb) {
    __shared__ int sm[256];
    int tid = threadIdx.x;
    int v = (tid < nb) ? blocksum[tid] : 0;
    sm[tid] = v;
    __syncthreads();
    #pragma unroll
    for (int d = 1; d < 256; d <<= 1) {
        int t = (tid >= d) ? sm[tid - d] : 0;
        __syncthreads();
        sm[tid] += t;
        __syncthreads();
    }
    if (tid < nb) blocksum[tid] = sm[tid] - v;     // exclusive block offsets
}

// Phase 3: add block offsets; init the fill cursor and rowptr[n].
__global__ __launch_bounds__(256) void add_off(
    int* __restrict__ rowptr, int* __restrict__ cur,
    const int* __restrict__ blocksum, int n, int E)
{
    int i = blockIdx.x * 256 + threadIdx.x;
    if (i < n) {
        int r = rowptr[i] + blocksum[blockIdx.x];
        rowptr[i] = r;
        cur[i] = r;
    }
    if (i == 0) rowptr[n] = E;   // all dst are in-range by construction
}

// XCD-partitioned fill (see R2 note): blockIdx&7 selects a dst-range so each
// XCD dirties only its own slice of csr -> one writeback per line.
__global__ void fill_k(const int* __restrict__ src, const int* __restrict__ dst,
                       int* __restrict__ cur, int* __restrict__ csr, int E, int N) {
    int part  = blockIdx.x & 7;
    int chunk = blockIdx.x >> 3;
    int e = chunk * 256 + threadIdx.x;
    int lo = (int)(((long long)part * N) >> 3);
    int hi = (int)(((long long)(part + 1) * N) >> 3);
    if (e < E) {
        int d = dst[e];
        if (d >= lo && d < hi) {
            int p = atomicAdd(&cur[d], 1);
            csr[p] = src[e];
        }
    }
}

// ---------------- MFMA GEMM -------------------------------------------------------
// out[i][j] = half( dinv[i] * sum_k X[i][k] W[k][j] ), output in SLICED layout:
// out_s[s][i][c] with s=j>>5, c=j&31 (4 arrays of M x 32 halves) so the gather
// kernel can pin one 3.2MB slice per XCD L2. A-input (layer 2) is also sliced.
// mfma_f32_16x16x32_f16: A[m=lane&15][k=quad*8+j]; B[k=quad*8+j][n=lane&15];
// D: row=quad*4+reg, col=lane&15.

template<bool F32IN>
__global__ __launch_bounds__(256) void mfma_gemm(
    const void* __restrict__ Xv, const __half* __restrict__ WT,
    const float* __restrict__ dinv, __half* __restrict__ out, int M)
{
    __shared__ __half wlds[128][136];   // pitch 272B: 16B-aligned, <=2-way banks
    const int tid = threadIdx.x;

    {   // stage WT (128x128 halves): 2 threads/row, 64 halves (8 x half8) each
        int r = tid >> 1;
        int c0 = (tid & 1) * 64;
        const half8* s = (const half8*)(WT + (size_t)r * NF + c0);
        half8* d = (half8*)&wlds[r][c0];
        #pragma unroll
        for (int j = 0; j < 8; j++) d[j] = s[j];
    }
    __syncthreads();

    const int wave = tid >> 6, lane = tid & 63;
    const int quad = lane >> 4, l15 = lane & 15;
    const int rowA = blockIdx.x * 64 + wave * 16 + l15;
    const int rowc = (rowA < M) ? rowA : (M - 1);   // clamp (dup row, never stored)
    const size_t sliceStride = (size_t)M * 32;

    half8 afr[4];
    if (F32IN) {
        const float* X = (const float*)Xv;   // row-major M x 128 fp32
        #pragma unroll
        for (int kc = 0; kc < 4; kc++) {
            const floatx4* p = (const floatx4*)(X + (size_t)rowc * NF + kc * 32 + quad * 8);
            floatx4 u = p[0], v = p[1];
            half8 a;
            a[0] = (_Float16)u[0]; a[1] = (_Float16)u[1];
            a[2] = (_Float16)u[2]; a[3] = (_Float16)u[3];
            a[4] = (_Float16)v[0]; a[5] = (_Float16)v[1];
            a[6] = (_Float16)v[2]; a[7] = (_Float16)v[3];
            afr[kc] = a;
        }
    } else {
        const __half* X = (const __half*)Xv;  // sliced: 4 arrays of M x 32 halves
        #pragma unroll
        for (int kc = 0; kc < 4; kc++)
            afr[kc] = *(const half8*)(X + (size_t)kc * sliceStride + (size_t)rowc * 32 + quad * 8);
    }

    floatx4 acc[8];
    #pragma unroll
    for (int ct = 0; ct < 8; ct++) { floatx4 z = {0.f, 0.f, 0.f, 0.f}; acc[ct] = z; }

    #pragma unroll
    for (int kc = 0; kc < 4; kc++) {
        #pragma unroll
        for (int ct = 0; ct < 8; ct++) {
            half8 b = *(const half8*)&wlds[ct * 16 + l15][kc * 32 + quad * 8];
            acc[ct] = __builtin_amdgcn_mfma_f32_16x16x32_f16(afr[kc], b, acc[ct], 0, 0, 0);
        }
    }

    const int orow0 = blockIdx.x * 64 + wave * 16 + quad * 4;
    #pragma unroll
    for (int r = 0; r < 4; r++) {
        int orow = orow0 + r;
        if (orow < M) {
            float s = dinv[orow];
            #pragma unroll
            for (int ct = 0; ct < 8; ct++) {
                // col = ct*16+l15 -> slice ct>>1, col-in-slice (ct&1)*16+l15
                out[(size_t)(ct >> 1) * sliceStride + (size_t)orow * 32 + (ct & 1) * 16 + l15]
                    = __float2half(acc[ct][r] * s);
            }
        }
    }
}

// ---------------- Aggregation: XCD-sliced gather ---------------------------------
// Slice s = blockIdx&3; block->XCD is round-robin %8, so XCD j only touches
// slice j&3 (3.2MB -> resident in its 4MB L2). Wave per node per slice; lane
// group eg=lane>>4 handles edge j+eg, lanes' fl=lane&15 index the 16 half2 of
// the slice. 4 edges per load instr (4 x 64B segments). After the edge loop a
// 2-step shfl_xor folds the 4 edge groups; lanes 0..15 write 32 features.
// acc = self + sum_in-edges; res = dinv[node]*acc + bias (relu for layer 1).

__global__ __launch_bounds__(512) void agg_k(
    const __half* __restrict__ hs, const int* __restrict__ rowptr,
    const int* __restrict__ csr, const float* __restrict__ dinv,
    const float* __restrict__ bias, __half* __restrict__ outh,
    float* __restrict__ outf, int n)
{
    const int s    = blockIdx.x & 3;      // slice (XCD-bound)
    const int grp  = blockIdx.x >> 2;
    const int wave = threadIdx.x >> 6;
    const int lane = threadIdx.x & 63;
    const int node = grp * 8 + wave;
    if (node >= n) return;
    const int eg = lane >> 4, fl = lane & 15;

    const size_t sliceStride2 = (size_t)n * 16;   // in half2 units
    const __half2* hsS = (const __half2*)hs + (size_t)s * sliceStride2;

    float2 acc = make_float2(0.f, 0.f);
    if (eg == 0) acc = __half22float2(hsS[(size_t)node * 16 + fl]);  // self-loop once

    int base = rowptr[node];
    int cnt  = rowptr[node + 1] - base;

    for (int off = 0; off < cnt; off += 64) {
        int m = min(64, cnt - off);
        int idx = 0;
        if (lane < m) idx = __builtin_nontemporal_load(&csr[base + off + lane]);
        for (int j = 0; j < m; j += 16) {
            int e0 = j + eg, e1 = j + 4 + eg, e2 = j + 8 + eg, e3 = j + 12 + eg;
            int s0 = __shfl(idx, min(e0, m - 1), 64);
            int s1 = __shfl(idx, min(e1, m - 1), 64);
            int s2 = __shfl(idx, min(e2, m - 1), 64);
            int s3 = __shfl(idx, min(e3, m - 1), 64);
            __half2 v0 = hsS[(size_t)s0 * 16 + fl];
            __half2 v1 = hsS[(size_t)s1 * 16 + fl];
            __half2 v2 = hsS[(size_t)s2 * 16 + fl];
            __half2 v3 = hsS[(size_t)s3 * 16 + fl];
            float2 f0 = __half22float2(v0), f1 = __half22float2(v1);
            float2 f2 = __half22float2(v2), f3 = __half22float2(v3);
            if (e0 < m) { acc.x += f0.x; acc.y += f0.y; }
            if (e1 < m) { acc.x += f1.x; acc.y += f1.y; }
            if (e2 < m) { acc.x += f2.x; acc.y += f2.y; }
            if (e3 < m) { acc.x += f3.x; acc.y += f3.y; }
        }
    }

    // fold the 4 edge-groups (lanes l, l^16, l^32, l^48)
    acc.x += __shfl_xor(acc.x, 16, 64);
    acc.y += __shfl_xor(acc.y, 16, 64);
    acc.x += __shfl_xor(acc.x, 32, 64);
    acc.y += __shfl_xor(acc.y, 32, 64);

    if (eg == 0) {
        float dv = dinv[node];
        float ox = dv * acc.x + bias[s * 32 + 2 * fl];
        float oy = dv * acc.y + bias[s * 32 + 2 * fl + 1];
        if (outh) {
            ox = fmaxf(ox, 0.f); oy = fmaxf(oy, 0.f);
            __half2 hv = __floats2half2_rn(ox, oy);
            unsigned int bits;
            __builtin_memcpy(&bits, &hv, 4);
            unsigned int* oS = (unsigned int*)outh + (size_t)s * sliceStride2;
            __builtin_nontemporal_store(bits, &oS[(size_t)node * 16 + fl]);
        } else {
            floatx2 w = { ox, oy };
            floatx2* op = (floatx2*)(outf + (size_t)node * NF + s * 32) + fl;
            __builtin_nontemporal_store(w, op);
        }
    }
}

// ---------------- launch ----------------

extern "C" void kernel_launch(void* const* d_in, const int* in_sizes, int n_in,
                              void* d_out, int out_size, void* d_ws, size_t ws_size,
                              hipStream_t stream) {
    const float* x  = (const float*)d_in[0];
    const int*   ei = (const int*)d_in[1];
    const float* W1 = (const float*)d_in[2];
    const float* b1 = (const float*)d_in[3];
    const float* W2 = (const float*)d_in[4];
    const float* b2 = (const float*)d_in[5];
    float* out = (float*)d_out;

    const int N = in_sizes[0] / NF;   // 50000
    const int E = in_sizes[1] / 2;    // 800000
    const int* src = ei;
    const int* dst = ei + E;

    char* ws = (char*)d_ws;
    size_t off = 0;
    auto alloc = [&](size_t bytes) {
        void* p = ws + off;
        off += bytes;
        off = (off + 63) & ~(size_t)63;
        return p;
    };
    int*    cnt    = (int*)alloc((size_t)N * 4);        // reused as fill cursor
    int*    rowptr = (int*)alloc((size_t)(N + 1) * 4);
    int*    csr    = (int*)alloc((size_t)E * 4);
    float*  dinv   = (float*)alloc((size_t)N * 4);
    int*    bsum   = (int*)alloc((size_t)256 * 4);
    __half* WT1    = (__half*)alloc((size_t)NF * NF * 2);
    __half* WT2    = (__half*)alloc((size_t)NF * NF * 2);
    __half* H16    = (__half*)alloc((size_t)N * NF * 2);  // 4 slices of N x 32
    __half* A16    = (__half*)alloc((size_t)N * NF * 2);  // 4 slices of N x 32

    int nb = (N + 255) / 256;     // 196 blocks (<= 256, required by scan_blk)
    int eb = (E + 255) / 256;

    prep_k<<<nb + 128, 256, 0, stream>>>(cnt, N, nb, W1, W2, WT1, WT2);
    count_k<<<eb, 256, 0, stream>>>(dst, cnt, E, N);
    pscan_local<<<nb, 256, 0, stream>>>(cnt, dinv, rowptr, bsum, N);
    scan_blk<<<1, 256, 0, stream>>>(bsum, nb);
    add_off<<<nb, 256, 0, stream>>>(rowptr, cnt, bsum, N, E);
    fill_k<<<eb * 8, 256, 0, stream>>>(src, dst, cnt, csr, E, N);

    int gb = (N + 63) / 64;
    int ab = ((N + 7) / 8) * 4;   // 4 slice-blocks per 8-node group
    mfma_gemm<true><<<gb, 256, 0, stream>>>(x, WT1, dinv, H16, N);
    agg_k<<<ab, 512, 0, stream>>>(H16, rowptr, csr, dinv, b1, A16, nullptr, N);
    mfma_gemm<false><<<gb, 256, 0, stream>>>(A16, WT2, dinv, H16, N);
    agg_k<<<ab, 512, 0, stream>>>(H16, rowptr, csr, dinv, b2, nullptr, out, N);
}

// Round 8
// 244.832 us; speedup vs baseline: 1.4190x; 1.4190x over previous
//
#include <hip/hip_runtime.h>
#include <hip/hip_fp16.h>

#define NF 128   // feature dim, fixed by the problem

typedef _Float16 half8 __attribute__((ext_vector_type(8)));
typedef float    floatx4 __attribute__((ext_vector_type(4)));

// ---------------- prep: zero cnt + convert/transpose W1,W2 to fp16 ----------------
__global__ __launch_bounds__(256) void prep_k(
    int* __restrict__ cnt, int n, int nb,
    const float* __restrict__ W1, const float* __restrict__ W2,
    __half* __restrict__ WT1, __half* __restrict__ WT2)
{
    int b = blockIdx.x;
    if (b < nb) {
        int i = b * 256 + threadIdx.x;
        if (i < n) cnt[i] = 0;
    } else {
        int idx = (b - nb) * 256 + threadIdx.x;   // 0..32767
        const float* W = (idx < 16384) ? W1 : W2;
        __half* WT     = (idx < 16384) ? WT1 : WT2;
        int j = idx & 16383;
        int nn = j & 127, k = j >> 7;
        WT[nn * NF + k] = __float2half(W[k * NF + nn]);   // WT[n][k] = W[k][n]
    }
}

// ---------------- count: 4 edges/thread (dst guaranteed in [0,N)) ----------------
__global__ __launch_bounds__(256) void count_k(const int* __restrict__ dst,
                                               int* __restrict__ cnt, int E) {
    int e = (blockIdx.x * 256 + threadIdx.x) * 4;
    if (e + 3 < E) {
        int4 d = *(const int4*)(dst + e);
        atomicAdd(&cnt[d.x], 1); atomicAdd(&cnt[d.y], 1);
        atomicAdd(&cnt[d.z], 1); atomicAdd(&cnt[d.w], 1);
    } else {
        for (int k = e; k < E; k++) atomicAdd(&cnt[dst[k]], 1);
    }
}

// Phase 1: per-256-chunk local exclusive scan (into rowptr) + block totals + dinv.
__global__ __launch_bounds__(256) void pscan_local(
    const int* __restrict__ cnt, float* __restrict__ dinv,
    int* __restrict__ rowptr, int* __restrict__ blocksum, int n)
{
    __shared__ int sm[256];
    int tid = threadIdx.x;
    int i = blockIdx.x * 256 + tid;
    int v = (i < n) ? cnt[i] : 0;
    if (i < n) dinv[i] = rsqrtf((float)v + 1.0f);  // +1 = self-loop
    sm[tid] = v;
    __syncthreads();
    #pragma unroll
    for (int d = 1; d < 256; d <<= 1) {
        int t = (tid >= d) ? sm[tid - d] : 0;
        __syncthreads();
        sm[tid] += t;
        __syncthreads();
    }
    if (i < n) rowptr[i] = sm[tid] - v;            // local exclusive prefix
    if (tid == 255) blocksum[blockIdx.x] = sm[255];
}

// Phase 2+3 fused: each block reduces blocksum[0..blockIdx) itself (nb<=256),
// adds the offset, inits the fill cursor and rowptr[n].
__global__ __launch_bounds__(256) void add_off2(
    int* __restrict__ rowptr, int* __restrict__ cur,
    const int* __restrict__ blocksum, int n, int E, int nb)
{
    __shared__ int sm[256];
    int tid = threadIdx.x;
    sm[tid] = (tid < nb && tid < (int)blockIdx.x) ? blocksum[tid] : 0;
    __syncthreads();
    #pragma unroll
    for (int d = 128; d > 0; d >>= 1) {
        if (tid < d) sm[tid] += sm[tid + d];
        __syncthreads();
    }
    int offv = sm[0];   // exclusive prefix of block sums
    int i = blockIdx.x * 256 + tid;
    if (i < n) {
        int r = rowptr[i] + offv;
        rowptr[i] = r;
        cur[i] = r;
    }
    if (blockIdx.x == 0 && tid == 0) rowptr[n] = E;
}

// ---------------- MFMA GEMM body (plain row-major N x 128 fp16 output) ----------
// out[i][j] = half( dinv[i] * sum_k X[i][k] W[k][j] )
// mfma_f32_16x16x32_f16: A[m=lane&15][k=quad*8+j]; B[k=quad*8+j][n=lane&15];
// D: row=quad*4+reg, col=lane&15.

template<bool F32IN>
__device__ __forceinline__ void gemm_body(
    const void* __restrict__ Xv, const __half* __restrict__ WT,
    const float* __restrict__ dinv, __half* __restrict__ out, int M, int bid)
{
    __shared__ __half wlds[128][136];   // pitch 272B: 16B-aligned, <=2-way banks
    const int tid = threadIdx.x;

    {   // stage WT (128x128 halves): 2 threads/row, 64 halves (8 x half8) each
        int r = tid >> 1;
        int c0 = (tid & 1) * 64;
        const half8* s = (const half8*)(WT + (size_t)r * NF + c0);
        half8* d = (half8*)&wlds[r][c0];
        #pragma unroll
        for (int j = 0; j < 8; j++) d[j] = s[j];
    }
    __syncthreads();

    const int wave = tid >> 6, lane = tid & 63;
    const int quad = lane >> 4, l15 = lane & 15;
    const int rowA = bid * 64 + wave * 16 + l15;
    const int rowc = (rowA < M) ? rowA : (M - 1);   // clamp (dup row, never stored)

    half8 afr[4];
    if (F32IN) {
        const float* X = (const float*)Xv;
        #pragma unroll
        for (int kc = 0; kc < 4; kc++) {
            const floatx4* p = (const floatx4*)(X + (size_t)rowc * NF + kc * 32 + quad * 8);
            floatx4 u = p[0], v = p[1];
            half8 a;
            a[0] = (_Float16)u[0]; a[1] = (_Float16)u[1];
            a[2] = (_Float16)u[2]; a[3] = (_Float16)u[3];
            a[4] = (_Float16)v[0]; a[5] = (_Float16)v[1];
            a[6] = (_Float16)v[2]; a[7] = (_Float16)v[3];
            afr[kc] = a;
        }
    } else {
        const __half* X = (const __half*)Xv;
        #pragma unroll
        for (int kc = 0; kc < 4; kc++)
            afr[kc] = *(const half8*)(X + (size_t)rowc * NF + kc * 32 + quad * 8);
    }

    floatx4 acc[8];
    #pragma unroll
    for (int ct = 0; ct < 8; ct++) { floatx4 z = {0.f, 0.f, 0.f, 0.f}; acc[ct] = z; }

    #pragma unroll
    for (int kc = 0; kc < 4; kc++) {
        #pragma unroll
        for (int ct = 0; ct < 8; ct++) {
            half8 b = *(const half8*)&wlds[ct * 16 + l15][kc * 32 + quad * 8];
            acc[ct] = __builtin_amdgcn_mfma_f32_16x16x32_f16(afr[kc], b, acc[ct], 0, 0, 0);
        }
    }

    const int orow0 = bid * 64 + wave * 16 + quad * 4;
    #pragma unroll
    for (int r = 0; r < 4; r++) {
        int orow = orow0 + r;
        if (orow < M) {
            float s = dinv[orow];
            #pragma unroll
            for (int ct = 0; ct < 8; ct++)
                out[(size_t)orow * NF + ct * 16 + l15] = __float2half(acc[ct][r] * s);
        }
    }
}

// Fused: blocks [0, gemmBlocks) run layer-1 GEMM (long, MFMA-bound, dispatched
// first); the rest run the XCD-partitioned CSR fill (short, atomic/latency-
// bound). Independent outputs (H16 vs csr), both deps (add_off2, prep) met.
__global__ __launch_bounds__(256) void fill_gemm1_k(
    const int* __restrict__ src, const int* __restrict__ dst,
    int* __restrict__ cur, int* __restrict__ csr, int E, int N,
    const float* __restrict__ X, const __half* __restrict__ WT,
    const float* __restrict__ dinv, __half* __restrict__ H, int gemmBlocks)
{
    int bid = blockIdx.x;
    if (bid < gemmBlocks) {
        gemm_body<true>(X, WT, dinv, H, N, bid);
    } else {
        int b = bid - gemmBlocks;
        int part = b & 7, chunk = b >> 3;   // part<->XCD is a fixed bijection
        int e = chunk * 256 + threadIdx.x;
        int lo = (int)(((long long)part * N) >> 3);
        int hi = (int)(((long long)(part + 1) * N) >> 3);
        if (e < E) {
            int d = dst[e];
            if (d >= lo && d < hi) {
                int p = atomicAdd(&cur[d], 1);
                csr[p] = src[e];
            }
        }
    }
}

__global__ __launch_bounds__(256) void gemm2_k(
    const __half* __restrict__ A, const __half* __restrict__ WT,
    const float* __restrict__ dinv, __half* __restrict__ H, int M)
{
    gemm_body<false>(A, WT, dinv, H, M, blockIdx.x);
}

// ---------------- Aggregation: one wave per node, fp16 gather, fp32 accumulate --
// R4 shape (proven) + 16-deep load pipeline. acc = hs[node] + sum_in hs[src];
// res = dinv[node]*acc + bias. outh: half(relu(res)) (layer 1); else float res.

__global__ __launch_bounds__(256) void agg_k(
    const __half2* __restrict__ hs, const int* __restrict__ rowptr,
    const int* __restrict__ csr, const float* __restrict__ dinv,
    const float* __restrict__ bias, __half2* __restrict__ outh,
    float* __restrict__ outf, int n)
{
    int wave = threadIdx.x >> 6;
    int lane = threadIdx.x & 63;
    int node = blockIdx.x * 4 + wave;
    if (node >= n) return;

    const int HS = NF / 2;   // 64 half2 per row
    float2 acc = __half22float2(hs[(size_t)node * HS + lane]);  // self-loop

    int base = rowptr[node];
    int cnt  = rowptr[node + 1] - base;

    for (int off = 0; off < cnt; off += 64) {
        int m = min(64, cnt - off);
        int idx = 0;
        if (lane < m) idx = __builtin_nontemporal_load(&csr[base + off + lane]);
        int j = 0;
        for (; j + 15 < m; j += 16) {   // 16 gathers in flight
            int s[16];
            __half2 v[16];
            #pragma unroll
            for (int t = 0; t < 16; t++) s[t] = __shfl(idx, j + t, 64);
            #pragma unroll
            for (int t = 0; t < 16; t++) v[t] = hs[(size_t)s[t] * HS + lane];
            #pragma unroll
            for (int t = 0; t < 16; t++) {
                float2 f = __half22float2(v[t]);
                acc.x += f.x; acc.y += f.y;
            }
        }
        for (; j + 3 < m; j += 4) {     // 4-deep remainder
            int s0 = __shfl(idx, j, 64);
            int s1 = __shfl(idx, j + 1, 64);
            int s2 = __shfl(idx, j + 2, 64);
            int s3 = __shfl(idx, j + 3, 64);
            __half2 v0 = hs[(size_t)s0 * HS + lane];
            __half2 v1 = hs[(size_t)s1 * HS + lane];
            __half2 v2 = hs[(size_t)s2 * HS + lane];
            __half2 v3 = hs[(size_t)s3 * HS + lane];
            float2 f0 = __half22float2(v0), f1 = __half22float2(v1);
            float2 f2 = __half22float2(v2), f3 = __half22float2(v3);
            acc.x += (f0.x + f1.x) + (f2.x + f3.x);
            acc.y += (f0.y + f1.y) + (f2.y + f3.y);
        }
        for (; j < m; j++) {
            int s0 = __shfl(idx, j, 64);
            float2 f0 = __half22float2(hs[(size_t)s0 * HS + lane]);
            acc.x += f0.x; acc.y += f0.y;
        }
    }

    float s = dinv[node];
    float ox = s * acc.x + bias[2 * lane];
    float oy = s * acc.y + bias[2 * lane + 1];
    if (outh) {
        ox = fmaxf(ox, 0.f); oy = fmaxf(oy, 0.f);
        outh[(size_t)node * HS + lane] = __floats2half2_rn(ox, oy);
    } else {
        ((float2*)(outf + (size_t)node * NF))[lane] = make_float2(ox, oy);
    }
}

// ---------------- launch ----------------

extern "C" void kernel_launch(void* const* d_in, const int* in_sizes, int n_in,
                              void* d_out, int out_size, void* d_ws, size_t ws_size,
                              hipStream_t stream) {
    const float* x  = (const float*)d_in[0];
    const int*   ei = (const int*)d_in[1];
    const float* W1 = (const float*)d_in[2];
    const float* b1 = (const float*)d_in[3];
    const float* W2 = (const float*)d_in[4];
    const float* b2 = (const float*)d_in[5];
    float* out = (float*)d_out;

    const int N = in_sizes[0] / NF;   // 50000
    const int E = in_sizes[1] / 2;    // 800000
    const int* src = ei;
    const int* dst = ei + E;

    char* ws = (char*)d_ws;
    size_t off = 0;
    auto alloc = [&](size_t bytes) {
        void* p = ws + off;
        off += bytes;
        off = (off + 63) & ~(size_t)63;
        return p;
    };
    int*    cnt    = (int*)alloc((size_t)N * 4);        // reused as fill cursor
    int*    rowptr = (int*)alloc((size_t)(N + 1) * 4);
    int*    csr    = (int*)alloc((size_t)E * 4);
    float*  dinv   = (float*)alloc((size_t)N * 4);
    int*    bsum   = (int*)alloc((size_t)256 * 4);
    __half* WT1    = (__half*)alloc((size_t)NF * NF * 2);
    __half* WT2    = (__half*)alloc((size_t)NF * NF * 2);
    __half* H16    = (__half*)alloc((size_t)N * NF * 2);
    __half* A16    = (__half*)alloc((size_t)N * NF * 2);

    int nb = (N + 255) / 256;     // 196 blocks (<= 256, required by add_off2)
    int eb = (E + 255) / 256;
    int cb = (E / 4 + 255) / 256;
    int gb = (N + 63) / 64;
    int ab = (N + 3) / 4;

    prep_k<<<nb + 128, 256, 0, stream>>>(cnt, N, nb, W1, W2, WT1, WT2);
    count_k<<<cb, 256, 0, stream>>>(dst, cnt, E);
    pscan_local<<<nb, 256, 0, stream>>>(cnt, dinv, rowptr, bsum, N);
    add_off2<<<nb, 256, 0, stream>>>(rowptr, cnt, bsum, N, E, nb);
    fill_gemm1_k<<<gb + eb * 8, 256, 0, stream>>>(src, dst, cnt, csr, E, N,
                                                  x, WT1, dinv, H16, gb);
    agg_k<<<ab, 256, 0, stream>>>((const __half2*)H16, rowptr, csr, dinv, b1,
                                  (__half2*)A16, nullptr, N);
    gemm2_k<<<gb, 256, 0, stream>>>(A16, WT2, dinv, H16, N);
    agg_k<<<ab, 256, 0, stream>>>((const __half2*)H16, rowptr, csr, dinv, b2,
                                  nullptr, out, N);
}